// Round 3
// baseline (154.299 us; speedup 1.0000x reference)
//
#include <hip/hip_runtime.h>
#include <stdint.h>

#define BB 8
#define NSQ 262144   // 512*512
#define TT 1024
#define FF 8
#define CH 9         // 8 weight features + 1 count channel (exact in f32, counts < 2^24)

using ull = unsigned long long;

// Native LDS f32 atomic (ds_add_f32). Plain atomicAdd(float*) compiles to a
// ds_cmpst CAS retry loop on gfx950 unless unsafe-fp-atomics is on -- theory
// says that CAS loop is the entire 115us. unsafeAtomicAdd emits the native op.
__device__ inline void lds_fadd(float* p, float v) { unsafeAtomicAdd(p, v); }

// Order-preserving float->uint key packed with element index so min() matches
// stable argsort's first-occurrence-of-minimum.
__device__ inline ull pack_key(float v, unsigned idx) {
    unsigned u = __float_as_uint(v);
    unsigned key = (u & 0x80000000u) ? ~u : (u | 0x80000000u);
    return ((ull)key << 32) | (ull)idx;
}

// LDS: sbins 4 KB + sG 36 KB = 40960 B exactly -> 4 blocks/CU (160 KB LDS).
__global__ __launch_bounds__(256, 4) void hist_kernel(
    const float* __restrict__ inp, const float* __restrict__ bins,
    const float* __restrict__ wts,
    float* __restrict__ part,      // [B][CH][P][T]
    ull* __restrict__ partMin,     // [P][B]
    int P, int iters)
{
    __shared__ float sbins[TT];
    __shared__ float sG[TT * CH];

    int blk = blockIdx.x;
    int b = blk / P, p = blk % P;
    int tid = threadIdx.x;

    for (int i = tid; i < TT * CH; i += 256) sG[i] = 0.f;
    for (int i = tid; i < TT; i += 256) sbins[i] = bins[b * TT + i];
    __syncthreads();

    int epb = iters * 1024;                 // elements per block
    int e_base = p * epb;                   // element offset within batch
    const float4* inp4 = (const float4*)(inp + (size_t)b * NSQ + e_base);
    const float4* wp   = (const float4*)(wts + ((size_t)b * NSQ + e_base) * FF);

    ull lmin = ~0ull;
    for (int it = 0; it < iters; ++it) {
        int q = it * 256 + tid;             // float4 index within block's range
        float4 v = inp4[q];
        float4 w0a = wp[q*8+0], w0b = wp[q*8+1];
        float4 w1a = wp[q*8+2], w1b = wp[q*8+3];
        float4 w2a = wp[q*8+4], w2b = wp[q*8+5];
        float4 w3a = wp[q*8+6], w3b = wp[q*8+7];

        // 4 independent upper_bound searches, interleaved (4x ILP on the
        // dependent LDS-read chain). upper_bound: first idx with bins[idx] > v.
        int lo0 = 0, hi0 = TT, lo1 = 0, hi1 = TT;
        int lo2 = 0, hi2 = TT, lo3 = 0, hi3 = TT;
        #pragma unroll
        for (int lev = 0; lev < 10; ++lev) {
            int m0 = (lo0 + hi0) >> 1, m1 = (lo1 + hi1) >> 1;
            int m2 = (lo2 + hi2) >> 1, m3 = (lo3 + hi3) >> 1;
            float b0 = sbins[m0], b1 = sbins[m1], b2 = sbins[m2], b3 = sbins[m3];
            if (b0 <= v.x) lo0 = m0 + 1; else hi0 = m0;
            if (b1 <= v.y) lo1 = m1 + 1; else hi1 = m1;
            if (b2 <= v.z) lo2 = m2 + 1; else hi2 = m2;
            if (b3 <= v.w) lo3 = m3 + 1; else hi3 = m3;
        }

        unsigned e0 = (unsigned)(e_base + q * 4);
        lmin = min(lmin, pack_key(v.x, e0 + 0));
        lmin = min(lmin, pack_key(v.y, e0 + 1));
        lmin = min(lmin, pack_key(v.z, e0 + 2));
        lmin = min(lmin, pack_key(v.w, e0 + 3));

        if (lo0 < TT) {
            float* gp = &sG[lo0 * CH];
            lds_fadd(gp+0, w0a.x); lds_fadd(gp+1, w0a.y);
            lds_fadd(gp+2, w0a.z); lds_fadd(gp+3, w0a.w);
            lds_fadd(gp+4, w0b.x); lds_fadd(gp+5, w0b.y);
            lds_fadd(gp+6, w0b.z); lds_fadd(gp+7, w0b.w);
            lds_fadd(gp+8, 1.0f);
        }
        if (lo1 < TT) {
            float* gp = &sG[lo1 * CH];
            lds_fadd(gp+0, w1a.x); lds_fadd(gp+1, w1a.y);
            lds_fadd(gp+2, w1a.z); lds_fadd(gp+3, w1a.w);
            lds_fadd(gp+4, w1b.x); lds_fadd(gp+5, w1b.y);
            lds_fadd(gp+6, w1b.z); lds_fadd(gp+7, w1b.w);
            lds_fadd(gp+8, 1.0f);
        }
        if (lo2 < TT) {
            float* gp = &sG[lo2 * CH];
            lds_fadd(gp+0, w2a.x); lds_fadd(gp+1, w2a.y);
            lds_fadd(gp+2, w2a.z); lds_fadd(gp+3, w2a.w);
            lds_fadd(gp+4, w2b.x); lds_fadd(gp+5, w2b.y);
            lds_fadd(gp+6, w2b.z); lds_fadd(gp+7, w2b.w);
            lds_fadd(gp+8, 1.0f);
        }
        if (lo3 < TT) {
            float* gp = &sG[lo3 * CH];
            lds_fadd(gp+0, w3a.x); lds_fadd(gp+1, w3a.y);
            lds_fadd(gp+2, w3a.z); lds_fadd(gp+3, w3a.w);
            lds_fadd(gp+4, w3b.x); lds_fadd(gp+5, w3b.y);
            lds_fadd(gp+6, w3b.z); lds_fadd(gp+7, w3b.w);
            lds_fadd(gp+8, 1.0f);
        }
    }

    // wave-level packed-min reduce
    int lane = tid & 63, wv = tid >> 6;
    for (int off = 32; off > 0; off >>= 1) {
        unsigned hi32 = (unsigned)(lmin >> 32), lo32 = (unsigned)(lmin & 0xFFFFFFFFu);
        unsigned ohi = __shfl_down(hi32, off, 64);
        unsigned olo = __shfl_down(lo32, off, 64);
        ull other = ((ull)ohi << 32) | (ull)olo;
        if (other < lmin) lmin = other;
    }
    __syncthreads();                 // all LDS atomics done; sbins now dead
    if (lane == 0) ((ull*)sbins)[wv] = lmin;   // reuse sbins as 4-slot scratch
    __syncthreads();
    if (tid == 0) {
        ull m = ((ull*)sbins)[0];
        #pragma unroll
        for (int w = 1; w < 4; ++w) { ull t = ((ull*)sbins)[w]; if (t < m) m = t; }
        partMin[(size_t)p * BB + b] = m;
    }

    // writeback: part[(b*CH+c)*P + p][T] -- global coalesced over i;
    // LDS reads stride-9 (odd) -> conflict-free
    for (int c = 0; c < CH; ++c) {
        size_t gbase = (((size_t)b * CH + c) * P + p) * TT;
        for (int i = tid; i < TT; i += 256)
            part[gbase + i] = sG[i * CH + c];
    }
}

__global__ __launch_bounds__(256) void reduce_kernel(
    const float* __restrict__ part, float* __restrict__ red, int P)
{
    int idx = blockIdx.x * 256 + threadIdx.x;   // over B*CH*T = 73728
    if (idx >= BB * CH * TT) return;
    int bc = idx / TT, j = idx - bc * TT;
    const float* src = part + ((size_t)bc * P) * TT + j;
    float s = 0.f;
    for (int p = 0; p < P; ++p) s += src[(size_t)p * TT];
    red[idx] = s;                                // red layout [B][CH][T]
}

__global__ __launch_bounds__(1024) void finalize_kernel(
    const float* __restrict__ red, const ull* __restrict__ partMin,
    const float* __restrict__ wts, float* __restrict__ out, int P)
{
    int blk = blockIdx.x;
    int b = blk / FF, f = blk % FF;
    int j = threadIdx.x;
    __shared__ float buf[2][TT];
    __shared__ float scnt[TT];
    __shared__ ull smin[128];

    // parallel min over partMin[:,b]
    ull m = ~0ull;
    for (int p = j; p < P; p += 128) {
        ull t = partMin[(size_t)p * BB + b];
        if (t < m) m = t;
    }
    if (j < 128) smin[j] = m;
    __syncthreads();
    #pragma unroll
    for (int s = 64; s >= 1; s >>= 1) {
        if (j < s) { if (smin[j + s] < smin[j]) smin[j] = smin[j + s]; }
        __syncthreads();
    }
    unsigned minIdx = (unsigned)(smin[0] & 0xFFFFFFFFu);
    float wmin = wts[((size_t)b * NSQ + minIdx) * FF + f];

    // inclusive scan of counts (channel 8)
    buf[0][j] = red[((size_t)b * CH + FF) * TT + j];
    __syncthreads();
    int cur = 0;
    for (int off = 1; off < TT; off <<= 1) {
        float v = buf[cur][j];
        if (j >= off) v += buf[cur][j - off];
        buf[cur ^ 1][j] = v;
        cur ^= 1;
        __syncthreads();
    }
    scnt[j] = buf[cur][j];
    __syncthreads();

    // inclusive scan of this block's feature
    buf[0][j] = red[((size_t)b * CH + f) * TT + j];
    __syncthreads();
    cur = 0;
    for (int off = 1; off < TT; off <<= 1) {
        float v = buf[cur][j];
        if (j >= off) v += buf[cur][j - off];
        buf[cur ^ 1][j] = v;
        cur ^= 1;
        __syncthreads();
    }
    float Cj   = buf[cur][j];
    float Cjm1 = (j > 0) ? buf[cur][j - 1] : 0.f;
    float scj   = scnt[j];
    float scjm1 = (j > 0) ? scnt[j - 1] : 1.f;   // unused when j==0
    // reference quirk: idx = clip(counts-1, 0) -> counts==0 gathers
    // cumsum_w[0] == weight vector of the minimum element, not 0
    float csj   = (scj   == 0.f) ? wmin : Cj;
    float csjm1 = (j == 0) ? 0.f : ((scjm1 == 0.f) ? wmin : Cjm1);
    out[((size_t)b * TT + j) * FF + f] = csj - csjm1;
}

extern "C" void kernel_launch(void* const* d_in, const int* in_sizes, int n_in,
                              void* d_out, int out_size, void* d_ws, size_t ws_size,
                              hipStream_t stream)
{
    const float* inp  = (const float*)d_in[0];
    const float* bins = (const float*)d_in[1];
    const float* wts  = (const float*)d_in[2];
    float* out = (float*)d_out;

    // pick partial-count P (power of two) to fit workspace
    int P = 128;
    for (;;) {
        size_t need = (size_t)BB * CH * P * TT * 4   // part
                    + (size_t)BB * CH * TT * 4       // red
                    + (size_t)P * BB * 8             // partMin
                    + 1024;
        if (need <= ws_size || P == 1) break;
        P >>= 1;
    }

    char* w = (char*)d_ws;
    float* part    = (float*)w; w += (size_t)BB * CH * P * TT * 4;
    float* red     = (float*)w; w += (size_t)BB * CH * TT * 4;
    ull*   partMin = (ull*)w;

    int iters = NSQ / (P * 1024);   // elements per block = iters*1024, ILP4 per thread

    hist_kernel<<<dim3(BB * P), dim3(256), 0, stream>>>(
        inp, bins, wts, part, partMin, P, iters);
    reduce_kernel<<<dim3((BB * CH * TT + 255) / 256), dim3(256), 0, stream>>>(
        part, red, P);
    finalize_kernel<<<dim3(BB * FF), dim3(1024), 0, stream>>>(
        red, partMin, wts, out, P);
}

// Round 4
// 105.373 us; speedup vs baseline: 1.4643x; 1.4643x over previous
//
#include <hip/hip_runtime.h>
#include <hip/hip_fp16.h>
#include <stdint.h>

#define BB 8
#define NSQ 262144   // 512*512
#define TT 1024
#define FF 8
#define CH 9         // 8 weight features + 1 count channel
#define SGS 5        // u32 stride per bucket in accumulate LDS (odd -> bank spread)

using ull = unsigned long long;

// Order-preserving float->uint key packed with element index so min() matches
// stable argsort's first-occurrence-of-minimum.
__device__ inline ull pack_key(float v, unsigned idx) {
    unsigned u = __float_as_uint(v);
    unsigned key = (u & 0x80000000u) ? ~u : (u | 0x80000000u);
    return ((ull)key << 32) | (ull)idx;
}

// 32-bit LDS byte offset of a __shared__ pointer (generic -> addrspace(3) cast).
__device__ inline unsigned lds_addr(const void* p) {
    return (unsigned)(uintptr_t)(__attribute__((address_space(3))) const void*)p;
}

__device__ inline unsigned pack_h2(float a, float b) {
    __half2 h = __halves2half2(__float2half(a), __float2half(b));
    unsigned u; __builtin_memcpy(&u, &h, 4); return u;
}

// ---------------- Phase 1: bucketize (search only, no fp atomics) ----------
__global__ __launch_bounds__(256, 4) void bucketize_kernel(
    const float* __restrict__ inp, const float* __restrict__ bins,
    unsigned short* __restrict__ ids, float* __restrict__ part,
    ull* __restrict__ partMin, int P, int iters)
{
    __shared__ float sbins[TT];
    __shared__ unsigned scnt[TT];
    int b = blockIdx.x / P, p = blockIdx.x % P;
    int tid = threadIdx.x;

    for (int i = tid; i < TT; i += 256) { sbins[i] = bins[b * TT + i]; scnt[i] = 0u; }
    __syncthreads();

    int epb = iters * 1024;
    int e_base = p * epb;
    const float4* inp4 = (const float4*)(inp + (size_t)b * NSQ + e_base);
    ushort4* id4p = (ushort4*)(ids + (size_t)b * NSQ + e_base);

    ull lmin = ~0ull;
    for (int it = 0; it < iters; ++it) {
        int q = it * 256 + tid;
        float4 v = inp4[q];

        // 4 independent upper_bound searches (first idx with bins[idx] > v)
        int lo0 = 0, hi0 = TT, lo1 = 0, hi1 = TT;
        int lo2 = 0, hi2 = TT, lo3 = 0, hi3 = TT;
        #pragma unroll
        for (int lev = 0; lev < 10; ++lev) {
            int m0 = (lo0 + hi0) >> 1, m1 = (lo1 + hi1) >> 1;
            int m2 = (lo2 + hi2) >> 1, m3 = (lo3 + hi3) >> 1;
            float b0 = sbins[m0], b1 = sbins[m1], b2 = sbins[m2], b3 = sbins[m3];
            if (b0 <= v.x) lo0 = m0 + 1; else hi0 = m0;
            if (b1 <= v.y) lo1 = m1 + 1; else hi1 = m1;
            if (b2 <= v.z) lo2 = m2 + 1; else hi2 = m2;
            if (b3 <= v.w) lo3 = m3 + 1; else hi3 = m3;
        }

        unsigned e0 = (unsigned)(e_base + q * 4);
        lmin = min(lmin, pack_key(v.x, e0 + 0));
        lmin = min(lmin, pack_key(v.y, e0 + 1));
        lmin = min(lmin, pack_key(v.z, e0 + 2));
        lmin = min(lmin, pack_key(v.w, e0 + 3));

        ushort4 u4;
        u4.x = (unsigned short)lo0; u4.y = (unsigned short)lo1;
        u4.z = (unsigned short)lo2; u4.w = (unsigned short)lo3;
        id4p[q] = u4;

        if (lo0 < TT) atomicAdd(&scnt[lo0], 1u);
        if (lo1 < TT) atomicAdd(&scnt[lo1], 1u);
        if (lo2 < TT) atomicAdd(&scnt[lo2], 1u);
        if (lo3 < TT) atomicAdd(&scnt[lo3], 1u);
    }

    // wave-level packed-min reduce
    int lane = tid & 63, wv = tid >> 6;
    for (int off = 32; off > 0; off >>= 1) {
        unsigned hi32 = (unsigned)(lmin >> 32), lo32 = (unsigned)(lmin & 0xFFFFFFFFu);
        unsigned ohi = __shfl_down(hi32, off, 64);
        unsigned olo = __shfl_down(lo32, off, 64);
        ull other = ((ull)ohi << 32) | (ull)olo;
        if (other < lmin) lmin = other;
    }
    __syncthreads();
    if (lane == 0) ((ull*)sbins)[wv] = lmin;   // sbins dead; reuse as scratch
    __syncthreads();
    if (tid == 0) {
        ull m = ((ull*)sbins)[0];
        #pragma unroll
        for (int w = 1; w < 4; ++w) { ull t = ((ull*)sbins)[w]; if (t < m) m = t; }
        partMin[(size_t)p * BB + b] = m;
    }

    // counts -> part channel 8 (exact in f32)
    size_t gbase = (((size_t)b * CH + FF) * P + p) * TT;
    for (int i = tid; i < TT; i += 256) part[gbase + i] = (float)scnt[i];
}

// ---------------- Phase 2: accumulate (atomics only, streaming) ------------
// 2 lanes per element: lane half=0 handles channels 0..3, half=1 channels 4..7.
// Weight loads fully coalesced (consecutive lanes -> consecutive float4).
__global__ __launch_bounds__(256, 4) void accumulate_kernel(
    const unsigned short* __restrict__ ids, const float* __restrict__ wts,
    float* __restrict__ part, int P, int epb)
{
    __shared__ unsigned sG16[TT * SGS];   // half2 accumulators, 20 KB
    int b = blockIdx.x / P, p = blockIdx.x % P;
    int tid = threadIdx.x;

    for (int i = tid; i < TT * SGS; i += 256) sG16[i] = 0u;
    __syncthreads();

    int e_base = p * epb;
    const unsigned short* idp = ids + (size_t)b * NSQ + e_base;
    const float4* wp = (const float4*)(wts + ((size_t)b * NSQ + e_base) * FF);
    int half = tid & 1, slot = tid >> 1;      // element slot within 128-group
    int iters = epb >> 7;                     // epb/128, multiple of 4

    for (int it = 0; it < iters; it += 4) {
        int i0 = (it + 0) * 128 + slot, i1 = (it + 1) * 128 + slot;
        int i2 = (it + 2) * 128 + slot, i3 = (it + 3) * 128 + slot;
        unsigned lo0 = idp[i0], lo1 = idp[i1], lo2 = idp[i2], lo3 = idp[i3];
        float4 w0 = wp[(size_t)i0 * 2 + half];
        float4 w1 = wp[(size_t)i1 * 2 + half];
        float4 w2 = wp[(size_t)i2 * 2 + half];
        float4 w3 = wp[(size_t)i3 * 2 + half];

        if (lo0 < TT) {
            unsigned a = lds_addr(&sG16[lo0 * SGS + half * 2]);
            unsigned d0 = pack_h2(w0.x, w0.y), d1 = pack_h2(w0.z, w0.w);
            asm volatile("ds_pk_add_f16 %0, %1" :: "v"(a), "v"(d0) : "memory");
            asm volatile("ds_pk_add_f16 %0, %1 offset:4" :: "v"(a), "v"(d1) : "memory");
        }
        if (lo1 < TT) {
            unsigned a = lds_addr(&sG16[lo1 * SGS + half * 2]);
            unsigned d0 = pack_h2(w1.x, w1.y), d1 = pack_h2(w1.z, w1.w);
            asm volatile("ds_pk_add_f16 %0, %1" :: "v"(a), "v"(d0) : "memory");
            asm volatile("ds_pk_add_f16 %0, %1 offset:4" :: "v"(a), "v"(d1) : "memory");
        }
        if (lo2 < TT) {
            unsigned a = lds_addr(&sG16[lo2 * SGS + half * 2]);
            unsigned d0 = pack_h2(w2.x, w2.y), d1 = pack_h2(w2.z, w2.w);
            asm volatile("ds_pk_add_f16 %0, %1" :: "v"(a), "v"(d0) : "memory");
            asm volatile("ds_pk_add_f16 %0, %1 offset:4" :: "v"(a), "v"(d1) : "memory");
        }
        if (lo3 < TT) {
            unsigned a = lds_addr(&sG16[lo3 * SGS + half * 2]);
            unsigned d0 = pack_h2(w3.x, w3.y), d1 = pack_h2(w3.z, w3.w);
            asm volatile("ds_pk_add_f16 %0, %1" :: "v"(a), "v"(d0) : "memory");
            asm volatile("ds_pk_add_f16 %0, %1 offset:4" :: "v"(a), "v"(d1) : "memory");
        }
    }

    asm volatile("s_waitcnt lgkmcnt(0)" ::: "memory");  // drain asm ds ops
    __syncthreads();

    // readback: half2 partials -> f32 part channels 0..7
    for (int i = tid; i < TT; i += 256) {
        #pragma unroll
        for (int k = 0; k < 4; ++k) {
            unsigned u = sG16[i * SGS + k];
            __half2 h; __builtin_memcpy(&h, &u, 4);
            float2 f = __half22float2(h);
            part[(((size_t)b * CH + 2 * k    ) * P + p) * TT + i] = f.x;
            part[(((size_t)b * CH + 2 * k + 1) * P + p) * TT + i] = f.y;
        }
    }
}

__global__ __launch_bounds__(256) void reduce_kernel(
    const float* __restrict__ part, float* __restrict__ red, int P)
{
    int idx = blockIdx.x * 256 + threadIdx.x;   // over B*CH*T = 73728
    if (idx >= BB * CH * TT) return;
    int bc = idx / TT, j = idx - bc * TT;
    const float* src = part + ((size_t)bc * P) * TT + j;
    float s = 0.f;
    for (int p = 0; p < P; ++p) s += src[(size_t)p * TT];
    red[idx] = s;                                // red layout [B][CH][T]
}

__global__ __launch_bounds__(1024) void finalize_kernel(
    const float* __restrict__ red, const ull* __restrict__ partMin,
    const float* __restrict__ wts, float* __restrict__ out, int P)
{
    int blk = blockIdx.x;
    int b = blk / FF, f = blk % FF;
    int j = threadIdx.x;
    __shared__ float buf[2][TT];
    __shared__ float scnt[TT];
    __shared__ ull smin[128];

    ull m = ~0ull;
    for (int p = j; p < P; p += 128) {
        ull t = partMin[(size_t)p * BB + b];
        if (t < m) m = t;
    }
    if (j < 128) smin[j] = m;
    __syncthreads();
    #pragma unroll
    for (int s = 64; s >= 1; s >>= 1) {
        if (j < s) { if (smin[j + s] < smin[j]) smin[j] = smin[j + s]; }
        __syncthreads();
    }
    unsigned minIdx = (unsigned)(smin[0] & 0xFFFFFFFFu);
    float wmin = wts[((size_t)b * NSQ + minIdx) * FF + f];

    // inclusive scan of counts (channel 8)
    buf[0][j] = red[((size_t)b * CH + FF) * TT + j];
    __syncthreads();
    int cur = 0;
    for (int off = 1; off < TT; off <<= 1) {
        float v = buf[cur][j];
        if (j >= off) v += buf[cur][j - off];
        buf[cur ^ 1][j] = v;
        cur ^= 1;
        __syncthreads();
    }
    scnt[j] = buf[cur][j];
    __syncthreads();

    // inclusive scan of this block's feature
    buf[0][j] = red[((size_t)b * CH + f) * TT + j];
    __syncthreads();
    cur = 0;
    for (int off = 1; off < TT; off <<= 1) {
        float v = buf[cur][j];
        if (j >= off) v += buf[cur][j - off];
        buf[cur ^ 1][j] = v;
        cur ^= 1;
        __syncthreads();
    }
    float Cj   = buf[cur][j];
    float Cjm1 = (j > 0) ? buf[cur][j - 1] : 0.f;
    float scj   = scnt[j];
    float scjm1 = (j > 0) ? scnt[j - 1] : 1.f;   // unused when j==0
    // reference quirk: counts==0 gathers cumsum_w[0] == weight of min element
    float csj   = (scj   == 0.f) ? wmin : Cj;
    float csjm1 = (j == 0) ? 0.f : ((scjm1 == 0.f) ? wmin : Cjm1);
    out[((size_t)b * TT + j) * FF + f] = csj - csjm1;
}

extern "C" void kernel_launch(void* const* d_in, const int* in_sizes, int n_in,
                              void* d_out, int out_size, void* d_ws, size_t ws_size,
                              hipStream_t stream)
{
    const float* inp  = (const float*)d_in[0];
    const float* bins = (const float*)d_in[1];
    const float* wts  = (const float*)d_in[2];
    float* out = (float*)d_out;

    // pick partial-count P (power of two) to fit workspace
    int P = 128;
    for (;;) {
        size_t need = (size_t)BB * CH * P * TT * 4   // part
                    + (size_t)BB * CH * TT * 4       // red
                    + (size_t)P * BB * 8             // partMin
                    + (size_t)BB * NSQ * 2           // ids
                    + 1024;
        if (need <= ws_size || P == 1) break;
        P >>= 1;
    }

    char* w = (char*)d_ws;
    float* part    = (float*)w; w += (size_t)BB * CH * P * TT * 4;
    float* red     = (float*)w; w += (size_t)BB * CH * TT * 4;
    ull*   partMin = (ull*)w;   w += (size_t)P * BB * 8;
    unsigned short* ids = (unsigned short*)w;

    int epb = NSQ / P;
    int iters = epb / 1024;

    bucketize_kernel<<<dim3(BB * P), dim3(256), 0, stream>>>(
        inp, bins, ids, part, partMin, P, iters);
    accumulate_kernel<<<dim3(BB * P), dim3(256), 0, stream>>>(
        ids, wts, part, P, epb);
    reduce_kernel<<<dim3((BB * CH * TT + 255) / 256), dim3(256), 0, stream>>>(
        part, red, P);
    finalize_kernel<<<dim3(BB * FF), dim3(1024), 0, stream>>>(
        red, partMin, wts, out, P);
}

// Round 5
// 66.273 us; speedup vs baseline: 2.3282x; 1.5900x over previous
//
#include <hip/hip_runtime.h>
#include <stdint.h>

#define BB 8
#define NSQ 262144   // 512*512
#define TT 1024
#define FF 8
#define CH 9         // 8 weight features + 1 count channel

using ull = unsigned long long;

// Order-preserving float->uint key packed with element index so min() matches
// stable argsort's first-occurrence-of-minimum.
__device__ inline ull pack_key(float v, unsigned idx) {
    unsigned u = __float_as_uint(v);
    unsigned key = (u & 0x80000000u) ? ~u : (u | 0x80000000u);
    return ((ull)key << 32) | (ull)idx;
}

// First 5 binary-search levels as a register cndmask tree over the 31 static
// midpoint values (uniform per block). Reproduces exactly the compare sequence
// of the LDS loop (midpoints {(2k+1)<<(9-L)} verified), so semantics identical.
__device__ inline void tree5(float v, const float* __restrict__ cf,
                             int& lo_out, int& hi_out) {
    bool s0 = cf[0] <= v;
    float m1 = s0 ? cf[2] : cf[1];
    bool s1 = m1 <= v;
    float a2 = s1 ? cf[4] : cf[3];
    float b2 = s1 ? cf[6] : cf[5];
    float m2 = s0 ? b2 : a2;
    bool s2 = m2 <= v;
    float a3 = s2 ? cf[8]  : cf[7];
    float b3 = s2 ? cf[10] : cf[9];
    float c3 = s2 ? cf[12] : cf[11];
    float d3 = s2 ? cf[14] : cf[13];
    float e3 = s1 ? b3 : a3;
    float f3 = s1 ? d3 : c3;
    float m3 = s0 ? f3 : e3;
    bool s3 = m3 <= v;
    float a4 = s3 ? cf[16] : cf[15];
    float b4 = s3 ? cf[18] : cf[17];
    float c4 = s3 ? cf[20] : cf[19];
    float d4 = s3 ? cf[22] : cf[21];
    float e4 = s3 ? cf[24] : cf[23];
    float f4 = s3 ? cf[26] : cf[25];
    float g4 = s3 ? cf[28] : cf[27];
    float h4 = s3 ? cf[30] : cf[29];
    float i4 = s2 ? b4 : a4;
    float j4 = s2 ? d4 : c4;
    float k4 = s2 ? f4 : e4;
    float l4 = s2 ? h4 : g4;
    float n4 = s1 ? j4 : i4;
    float o4 = s1 ? l4 : k4;
    float m4 = s0 ? o4 : n4;
    bool s4 = m4 <= v;
    int lo = 0, hi = TT, m;
    m = (lo + hi) >> 1; lo = s0 ? m + 1 : lo; hi = s0 ? hi : m;
    m = (lo + hi) >> 1; lo = s1 ? m + 1 : lo; hi = s1 ? hi : m;
    m = (lo + hi) >> 1; lo = s2 ? m + 1 : lo; hi = s2 ? hi : m;
    m = (lo + hi) >> 1; lo = s3 ? m + 1 : lo; hi = s3 ? hi : m;
    m = (lo + hi) >> 1; lo = s4 ? m + 1 : lo; hi = s4 ? hi : m;
    lo_out = lo; hi_out = hi;
}

// ---------------- Phase 1: bucketize (search only) -------------------------
__global__ __launch_bounds__(256, 4) void bucketize_kernel(
    const float* __restrict__ inp, const float* __restrict__ bins,
    unsigned short* __restrict__ ids, float* __restrict__ part,
    ull* __restrict__ partMin, int P, int iters)
{
    __shared__ float sbins[TT];
    __shared__ unsigned scnt[TT];
    int b = blockIdx.x / P, p = blockIdx.x % P;
    int tid = threadIdx.x;

    for (int i = tid; i < TT; i += 256) { sbins[i] = bins[b * TT + i]; scnt[i] = 0u; }
    __syncthreads();

    // 31 coarse midpoints into registers (uniform broadcast reads)
    float cf[31];
    cf[0] = sbins[512]; cf[1] = sbins[256]; cf[2] = sbins[768];
    #pragma unroll
    for (int k = 0; k < 4; ++k)  cf[3 + k]  = sbins[128 + 256 * k];
    #pragma unroll
    for (int k = 0; k < 8; ++k)  cf[7 + k]  = sbins[64 + 128 * k];
    #pragma unroll
    for (int k = 0; k < 16; ++k) cf[15 + k] = sbins[32 + 64 * k];

    int epb = iters * 1024;
    int e_base = p * epb;
    const float4* inp4 = (const float4*)(inp + (size_t)b * NSQ + e_base);
    ushort4* id4p = (ushort4*)(ids + (size_t)b * NSQ + e_base);

    ull lmin = ~0ull;
    for (int it = 0; it < iters; ++it) {
        int q = it * 256 + tid;
        float4 v = inp4[q];

        int lo0, hi0, lo1, hi1, lo2, hi2, lo3, hi3;
        tree5(v.x, cf, lo0, hi0);
        tree5(v.y, cf, lo1, hi1);
        tree5(v.z, cf, lo2, hi2);
        tree5(v.w, cf, lo3, hi3);

        // 5 LDS levels, 4-way interleaved
        #pragma unroll
        for (int lev = 0; lev < 5; ++lev) {
            int m0 = (lo0 + hi0) >> 1, m1 = (lo1 + hi1) >> 1;
            int m2 = (lo2 + hi2) >> 1, m3 = (lo3 + hi3) >> 1;
            float b0 = sbins[m0], b1 = sbins[m1], b2 = sbins[m2], b3 = sbins[m3];
            if (b0 <= v.x) lo0 = m0 + 1; else hi0 = m0;
            if (b1 <= v.y) lo1 = m1 + 1; else hi1 = m1;
            if (b2 <= v.z) lo2 = m2 + 1; else hi2 = m2;
            if (b3 <= v.w) lo3 = m3 + 1; else hi3 = m3;
        }
        // fix-up: rare leaf where 10 levels leave 2 candidates
        if (lo0 < hi0 && sbins[lo0] <= v.x) ++lo0;
        if (lo1 < hi1 && sbins[lo1] <= v.y) ++lo1;
        if (lo2 < hi2 && sbins[lo2] <= v.z) ++lo2;
        if (lo3 < hi3 && sbins[lo3] <= v.w) ++lo3;

        unsigned e0 = (unsigned)(e_base + q * 4);
        lmin = min(lmin, pack_key(v.x, e0 + 0));
        lmin = min(lmin, pack_key(v.y, e0 + 1));
        lmin = min(lmin, pack_key(v.z, e0 + 2));
        lmin = min(lmin, pack_key(v.w, e0 + 3));

        ushort4 u4;
        u4.x = (unsigned short)lo0; u4.y = (unsigned short)lo1;
        u4.z = (unsigned short)lo2; u4.w = (unsigned short)lo3;
        id4p[q] = u4;

        if (lo0 < TT) atomicAdd(&scnt[lo0], 1u);
        if (lo1 < TT) atomicAdd(&scnt[lo1], 1u);
        if (lo2 < TT) atomicAdd(&scnt[lo2], 1u);
        if (lo3 < TT) atomicAdd(&scnt[lo3], 1u);
    }

    // wave-level packed-min reduce
    int lane = tid & 63, wv = tid >> 6;
    for (int off = 32; off > 0; off >>= 1) {
        unsigned hi32 = (unsigned)(lmin >> 32), lo32 = (unsigned)(lmin & 0xFFFFFFFFu);
        unsigned ohi = __shfl_down(hi32, off, 64);
        unsigned olo = __shfl_down(lo32, off, 64);
        ull other = ((ull)ohi << 32) | (ull)olo;
        if (other < lmin) lmin = other;
    }
    __syncthreads();
    if (lane == 0) ((ull*)sbins)[wv] = lmin;   // sbins dead; reuse as scratch
    __syncthreads();
    if (tid == 0) {
        ull m = ((ull*)sbins)[0];
        #pragma unroll
        for (int w = 1; w < 4; ++w) { ull t = ((ull*)sbins)[w]; if (t < m) m = t; }
        partMin[(size_t)p * BB + b] = m;
    }

    // counts -> part channel 8 (exact in f32)
    size_t gbase = (((size_t)b * CH + FF) * P + p) * TT;
    for (int i = tid; i < TT; i += 256) part[gbase + i] = (float)scnt[i];
}

// ---------------- Phase 2: accumulate (u64 packed fixed-point atomics) -----
// 2 lanes per element: half=0 -> channels 0..3, half=1 -> channels 4..7,
// each packed 4x16-bit (scale 1024) into ONE ds_add_u64.
__global__ __launch_bounds__(256, 4) void accumulate_kernel(
    const unsigned short* __restrict__ ids, const float* __restrict__ wts,
    float* __restrict__ part, int P, int epb)
{
    __shared__ ull sG[TT * 2];   // 16 KB
    int b = blockIdx.x / P, p = blockIdx.x % P;
    int tid = threadIdx.x;

    for (int i = tid; i < TT * 2; i += 256) sG[i] = 0ull;
    __syncthreads();

    int e_base = p * epb;
    const unsigned short* idp = ids + (size_t)b * NSQ + e_base;
    const float4* wp = (const float4*)(wts + ((size_t)b * NSQ + e_base) * FF);
    int half = tid & 1, slot = tid >> 1;
    int nchunk = epb >> 7;          // 128 elements per chunk

    #pragma unroll 4
    for (int it = 0; it < nchunk; ++it) {
        int i0 = it * 128 + slot;
        unsigned lo = idp[i0];
        float4 w = wp[(size_t)i0 * 2 + half];
        if (lo < TT) {
            ull q = (ull)(unsigned)__float2int_rn(w.x * 1024.f)
                  | ((ull)(unsigned)__float2int_rn(w.y * 1024.f) << 16)
                  | ((ull)(unsigned)__float2int_rn(w.z * 1024.f) << 32)
                  | ((ull)(unsigned)__float2int_rn(w.w * 1024.f) << 48);
            atomicAdd(&sG[lo * 2 + half], q);
        }
    }
    __syncthreads();

    // readback: exact integer sums -> f32 partials (scale back by 1/1024)
    const float inv = 1.0f / 1024.0f;
    for (int i = tid; i < TT; i += 256) {
        #pragma unroll
        for (int h = 0; h < 2; ++h) {
            ull u = sG[i * 2 + h];
            part[(((size_t)b * CH + 4*h + 0) * P + p) * TT + i] = (float)(unsigned)( u        & 0xFFFF) * inv;
            part[(((size_t)b * CH + 4*h + 1) * P + p) * TT + i] = (float)(unsigned)((u >> 16) & 0xFFFF) * inv;
            part[(((size_t)b * CH + 4*h + 2) * P + p) * TT + i] = (float)(unsigned)((u >> 32) & 0xFFFF) * inv;
            part[(((size_t)b * CH + 4*h + 3) * P + p) * TT + i] = (float)(unsigned)((u >> 48) & 0xFFFF) * inv;
        }
    }
}

__global__ __launch_bounds__(256) void reduce_kernel(
    const float* __restrict__ part, float* __restrict__ red, int P)
{
    int idx = blockIdx.x * 256 + threadIdx.x;   // over B*CH*T = 73728
    if (idx >= BB * CH * TT) return;
    int bc = idx / TT, j = idx - bc * TT;
    const float* src = part + ((size_t)bc * P) * TT + j;
    float s = 0.f;
    for (int p = 0; p < P; ++p) s += src[(size_t)p * TT];
    red[idx] = s;                                // red layout [B][CH][T]
}

__global__ __launch_bounds__(1024) void finalize_kernel(
    const float* __restrict__ red, const ull* __restrict__ partMin,
    const float* __restrict__ wts, float* __restrict__ out, int P)
{
    int blk = blockIdx.x;
    int b = blk / FF, f = blk % FF;
    int j = threadIdx.x;
    __shared__ float buf[2][TT];
    __shared__ float scnt[TT];
    __shared__ ull smin[128];

    ull m = ~0ull;
    for (int p = j; p < P; p += 128) {
        ull t = partMin[(size_t)p * BB + b];
        if (t < m) m = t;
    }
    if (j < 128) smin[j] = m;
    __syncthreads();
    #pragma unroll
    for (int s = 64; s >= 1; s >>= 1) {
        if (j < s) { if (smin[j + s] < smin[j]) smin[j] = smin[j + s]; }
        __syncthreads();
    }
    unsigned minIdx = (unsigned)(smin[0] & 0xFFFFFFFFu);
    float wmin = wts[((size_t)b * NSQ + minIdx) * FF + f];

    // inclusive scan of counts (channel 8)
    buf[0][j] = red[((size_t)b * CH + FF) * TT + j];
    __syncthreads();
    int cur = 0;
    for (int off = 1; off < TT; off <<= 1) {
        float v = buf[cur][j];
        if (j >= off) v += buf[cur][j - off];
        buf[cur ^ 1][j] = v;
        cur ^= 1;
        __syncthreads();
    }
    scnt[j] = buf[cur][j];
    __syncthreads();

    // inclusive scan of this block's feature
    buf[0][j] = red[((size_t)b * CH + f) * TT + j];
    __syncthreads();
    cur = 0;
    for (int off = 1; off < TT; off <<= 1) {
        float v = buf[cur][j];
        if (j >= off) v += buf[cur][j - off];
        buf[cur ^ 1][j] = v;
        cur ^= 1;
        __syncthreads();
    }
    float Cj   = buf[cur][j];
    float Cjm1 = (j > 0) ? buf[cur][j - 1] : 0.f;
    float scj   = scnt[j];
    float scjm1 = (j > 0) ? scnt[j - 1] : 1.f;   // unused when j==0
    // reference quirk: counts==0 gathers cumsum_w[0] == weight of min element
    float csj   = (scj   == 0.f) ? wmin : Cj;
    float csjm1 = (j == 0) ? 0.f : ((scjm1 == 0.f) ? wmin : Cjm1);
    out[((size_t)b * TT + j) * FF + f] = csj - csjm1;
}

extern "C" void kernel_launch(void* const* d_in, const int* in_sizes, int n_in,
                              void* d_out, int out_size, void* d_ws, size_t ws_size,
                              hipStream_t stream)
{
    const float* inp  = (const float*)d_in[0];
    const float* bins = (const float*)d_in[1];
    const float* wts  = (const float*)d_in[2];
    float* out = (float*)d_out;

    // pick partial-count P (power of two) to fit workspace
    int P = 64;
    for (;;) {
        size_t need = (size_t)BB * CH * P * TT * 4   // part
                    + (size_t)BB * CH * TT * 4       // red
                    + (size_t)P * BB * 8             // partMin
                    + (size_t)BB * NSQ * 2           // ids
                    + 1024;
        if (need <= ws_size || P == 1) break;
        P >>= 1;
    }

    char* w = (char*)d_ws;
    float* part    = (float*)w; w += (size_t)BB * CH * P * TT * 4;
    float* red     = (float*)w; w += (size_t)BB * CH * TT * 4;
    ull*   partMin = (ull*)w;   w += (size_t)P * BB * 8;
    unsigned short* ids = (unsigned short*)w;

    int epb = NSQ / P;
    int iters = epb / 1024;

    bucketize_kernel<<<dim3(BB * P), dim3(256), 0, stream>>>(
        inp, bins, ids, part, partMin, P, iters);
    accumulate_kernel<<<dim3(BB * P), dim3(256), 0, stream>>>(
        ids, wts, part, P, epb);
    reduce_kernel<<<dim3((BB * CH * TT + 255) / 256), dim3(256), 0, stream>>>(
        part, red, P);
    finalize_kernel<<<dim3(BB * FF), dim3(1024), 0, stream>>>(
        red, partMin, wts, out, P);
}

// Round 6
// 58.404 us; speedup vs baseline: 2.6419x; 1.1347x over previous
//
#include <hip/hip_runtime.h>
#include <stdint.h>

#define BB 8
#define NSQ 262144   // 512*512
#define TT 1024
#define FF 8
#define CH 9         // 8 weight features + 1 count channel
#define PP 64        // partials per batch
#define EPB 4096     // NSQ/PP elements per block
#define ITERS 4      // EPB/1024 float4-iterations per thread

using ull = unsigned long long;

// Order-preserving float->uint key packed with element index so min() matches
// stable argsort's first-occurrence-of-minimum.
__device__ inline ull pack_key(float v, unsigned idx) {
    unsigned u = __float_as_uint(v);
    unsigned key = (u & 0x80000000u) ? ~u : (u | 0x80000000u);
    return ((ull)key << 32) | (ull)idx;
}

// First 5 binary-search levels as a register cndmask tree over the 31 static
// midpoint values (uniform per block). Identical compare sequence to the LDS
// loop (midpoints {(2k+1)<<(9-L)}), so semantics identical. (proven R5)
__device__ inline void tree5(float v, const float* __restrict__ cf,
                             int& lo_out, int& hi_out) {
    bool s0 = cf[0] <= v;
    float m1 = s0 ? cf[2] : cf[1];
    bool s1 = m1 <= v;
    float a2 = s1 ? cf[4] : cf[3];
    float b2 = s1 ? cf[6] : cf[5];
    float m2 = s0 ? b2 : a2;
    bool s2 = m2 <= v;
    float a3 = s2 ? cf[8]  : cf[7];
    float b3 = s2 ? cf[10] : cf[9];
    float c3 = s2 ? cf[12] : cf[11];
    float d3 = s2 ? cf[14] : cf[13];
    float e3 = s1 ? b3 : a3;
    float f3 = s1 ? d3 : c3;
    float m3 = s0 ? f3 : e3;
    bool s3 = m3 <= v;
    float a4 = s3 ? cf[16] : cf[15];
    float b4 = s3 ? cf[18] : cf[17];
    float c4 = s3 ? cf[20] : cf[19];
    float d4 = s3 ? cf[22] : cf[21];
    float e4 = s3 ? cf[24] : cf[23];
    float f4 = s3 ? cf[26] : cf[25];
    float g4 = s3 ? cf[28] : cf[27];
    float h4 = s3 ? cf[30] : cf[29];
    float i4 = s2 ? b4 : a4;
    float j4 = s2 ? d4 : c4;
    float k4 = s2 ? f4 : e4;
    float l4 = s2 ? h4 : g4;
    float n4 = s1 ? j4 : i4;
    float o4 = s1 ? l4 : k4;
    float m4 = s0 ? o4 : n4;
    bool s4 = m4 <= v;
    int lo = 0, hi = TT, m;
    m = (lo + hi) >> 1; lo = s0 ? m + 1 : lo; hi = s0 ? hi : m;
    m = (lo + hi) >> 1; lo = s1 ? m + 1 : lo; hi = s1 ? hi : m;
    m = (lo + hi) >> 1; lo = s2 ? m + 1 : lo; hi = s2 ? hi : m;
    m = (lo + hi) >> 1; lo = s3 ? m + 1 : lo; hi = s3 ? hi : m;
    m = (lo + hi) >> 1; lo = s4 ? m + 1 : lo; hi = s4 ? hi : m;
    lo_out = lo; hi_out = hi;
}

// Fused: search + count + in-block counting-sort + owner register-summation.
// Atomic budget: 2 x 32-bit RMW units per element (count + cursor) vs 4 in R5.
__global__ __launch_bounds__(256, 4) void histo_kernel(
    const float* __restrict__ inp, const float* __restrict__ bins,
    const float* __restrict__ wts,
    float* __restrict__ part,      // [B][CH][PP][T]
    ull* __restrict__ partMin)     // [PP][B]
{
    __shared__ float sbins[TT];            // 4 KB
    __shared__ unsigned scnt[TT];          // 4 KB raw counts
    __shared__ unsigned sCur[TT];          // 4 KB prefix, then cursor
    __shared__ unsigned short sIdx[EPB];   // 8 KB sorted local element indices
    __shared__ ull sMinW[4];
    __shared__ unsigned sWs[4];

    int b = blockIdx.x / PP, p = blockIdx.x % PP;
    int tid = threadIdx.x;
    int lane = tid & 63, wv = tid >> 6;

    for (int i = tid; i < TT; i += 256) { sbins[i] = bins[b * TT + i]; scnt[i] = 0u; }
    __syncthreads();

    // 31 coarse midpoints into registers (uniform broadcast reads)
    float cf[31];
    cf[0] = sbins[512]; cf[1] = sbins[256]; cf[2] = sbins[768];
    #pragma unroll
    for (int k = 0; k < 4; ++k)  cf[3 + k]  = sbins[128 + 256 * k];
    #pragma unroll
    for (int k = 0; k < 8; ++k)  cf[7 + k]  = sbins[64 + 128 * k];
    #pragma unroll
    for (int k = 0; k < 16; ++k) cf[15 + k] = sbins[32 + 64 * k];

    const float4* inp4 = (const float4*)(inp + (size_t)b * NSQ + (size_t)p * EPB);

    // ---- Phase A: search + count (ids stay in registers) ----
    int ids[ITERS * 4];
    ull lmin = ~0ull;
    #pragma unroll
    for (int it = 0; it < ITERS; ++it) {
        int q = it * 256 + tid;
        float4 v = inp4[q];

        int lo0, hi0, lo1, hi1, lo2, hi2, lo3, hi3;
        tree5(v.x, cf, lo0, hi0);
        tree5(v.y, cf, lo1, hi1);
        tree5(v.z, cf, lo2, hi2);
        tree5(v.w, cf, lo3, hi3);
        #pragma unroll
        for (int lev = 0; lev < 5; ++lev) {
            int m0 = (lo0 + hi0) >> 1, m1 = (lo1 + hi1) >> 1;
            int m2 = (lo2 + hi2) >> 1, m3 = (lo3 + hi3) >> 1;
            float b0 = sbins[m0], b1 = sbins[m1], b2 = sbins[m2], b3 = sbins[m3];
            if (b0 <= v.x) lo0 = m0 + 1; else hi0 = m0;
            if (b1 <= v.y) lo1 = m1 + 1; else hi1 = m1;
            if (b2 <= v.z) lo2 = m2 + 1; else hi2 = m2;
            if (b3 <= v.w) lo3 = m3 + 1; else hi3 = m3;
        }
        if (lo0 < hi0 && sbins[lo0] <= v.x) ++lo0;
        if (lo1 < hi1 && sbins[lo1] <= v.y) ++lo1;
        if (lo2 < hi2 && sbins[lo2] <= v.z) ++lo2;
        if (lo3 < hi3 && sbins[lo3] <= v.w) ++lo3;

        unsigned e0 = (unsigned)(p * EPB + q * 4);
        lmin = min(lmin, pack_key(v.x, e0 + 0));
        lmin = min(lmin, pack_key(v.y, e0 + 1));
        lmin = min(lmin, pack_key(v.z, e0 + 2));
        lmin = min(lmin, pack_key(v.w, e0 + 3));

        ids[it * 4 + 0] = lo0; ids[it * 4 + 1] = lo1;
        ids[it * 4 + 2] = lo2; ids[it * 4 + 3] = lo3;

        if (lo0 < TT) atomicAdd(&scnt[lo0], 1u);
        if (lo1 < TT) atomicAdd(&scnt[lo1], 1u);
        if (lo2 < TT) atomicAdd(&scnt[lo2], 1u);
        if (lo3 < TT) atomicAdd(&scnt[lo3], 1u);
    }

    // wave-level packed-min reduce (pre-barrier; sMinW written by lane 0)
    for (int off = 32; off > 0; off >>= 1) {
        unsigned hi32 = (unsigned)(lmin >> 32), lo32 = (unsigned)(lmin & 0xFFFFFFFFu);
        unsigned ohi = __shfl_down(hi32, off, 64);
        unsigned olo = __shfl_down(lo32, off, 64);
        ull other = ((ull)ohi << 32) | (ull)olo;
        if (other < lmin) lmin = other;
    }
    if (lane == 0) sMinW[wv] = lmin;
    __syncthreads();   // counts + sMinW final

    if (tid == 0) {
        ull m = sMinW[0];
        #pragma unroll
        for (int w = 1; w < 4; ++w) { ull t = sMinW[w]; if (t < m) m = t; }
        partMin[(size_t)p * BB + b] = m;
    }

    // ---- counts -> global + exclusive prefix scan (1024 vals, 4/thread) ----
    int t4 = tid * 4;
    unsigned c0 = scnt[t4], c1 = scnt[t4 + 1], c2 = scnt[t4 + 2], c3 = scnt[t4 + 3];
    {
        float4 cf4 = make_float4((float)c0, (float)c1, (float)c2, (float)c3);
        float4* dst = (float4*)(part + (((size_t)b * CH + FF) * PP + p) * TT);
        dst[tid] = cf4;
    }
    unsigned l1 = c0 + c1, l2 = l1 + c2, l3 = l2 + c3;
    unsigned s = l3;
    #pragma unroll
    for (int off = 1; off < 64; off <<= 1) {
        unsigned n = __shfl_up(s, off, 64);
        if (lane >= off) s += n;
    }
    if (lane == 63) sWs[wv] = s;
    __syncthreads();
    unsigned wbase = 0;
    #pragma unroll
    for (int w = 0; w < 4; ++w) if (w < wv) wbase += sWs[w];
    unsigned tbase = wbase + s - l3;   // exclusive base of bucket t4
    sCur[t4 + 0] = tbase;
    sCur[t4 + 1] = tbase + c0;
    sCur[t4 + 2] = tbase + l1;
    sCur[t4 + 3] = tbase + l2;
    __syncthreads();

    // ---- Phase B: scatter local element indices into sorted order ----
    #pragma unroll
    for (int k = 0; k < ITERS * 4; ++k) {
        int id = ids[k];
        if (id < TT) {
            unsigned slot = atomicAdd(&sCur[id], 1u);
            sIdx[slot] = (unsigned short)((k >> 2) * 1024 + tid * 4 + (k & 3));
        }
    }
    __syncthreads();

    // ---- Phase C: bucket-owner register summation (no atomics) ----
    const float4* wv4 = (const float4*)(wts + ((size_t)b * NSQ + (size_t)p * EPB) * FF);
    #pragma unroll
    for (int k = 0; k < 4; ++k) {
        int t = tid + 256 * k;
        unsigned end = sCur[t];          // base + count after scatter
        unsigned cnt = scnt[t];
        unsigned start = end - cnt;
        float a0 = 0.f, a1 = 0.f, a2 = 0.f, a3 = 0.f;
        float a4 = 0.f, a5 = 0.f, a6 = 0.f, a7 = 0.f;
        for (unsigned e = start; e < end; ++e) {
            unsigned li = sIdx[e];
            float4 wa = wv4[(size_t)li * 2 + 0];
            float4 wb = wv4[(size_t)li * 2 + 1];
            a0 += wa.x; a1 += wa.y; a2 += wa.z; a3 += wa.w;
            a4 += wb.x; a5 += wb.y; a6 += wb.z; a7 += wb.w;
        }
        size_t pb = ((size_t)b * CH * PP + p) * TT + t;
        part[pb + 0 * PP * TT] = a0;
        part[pb + 1 * PP * TT] = a1;
        part[pb + 2 * PP * TT] = a2;
        part[pb + 3 * PP * TT] = a3;
        part[pb + 4 * PP * TT] = a4;
        part[pb + 5 * PP * TT] = a5;
        part[pb + 6 * PP * TT] = a6;
        part[pb + 7 * PP * TT] = a7;
    }
}

// Fused P-reduction + scans + output (one block per (b,f))
__global__ __launch_bounds__(1024) void finalize_kernel(
    const float* __restrict__ part, const ull* __restrict__ partMin,
    const float* __restrict__ wts, float* __restrict__ out)
{
    int blk = blockIdx.x;
    int b = blk / FF, f = blk % FF;
    int j = threadIdx.x;
    __shared__ float buf[2][TT];
    __shared__ float scnt[TT];
    __shared__ ull smin[128];

    // parallel min over partMin[:,b]
    ull m = ~0ull;
    for (int p = j; p < PP; p += 128) {
        ull t = partMin[(size_t)p * BB + b];
        if (t < m) m = t;
    }
    if (j < 128) smin[j] = m;
    __syncthreads();
    #pragma unroll
    for (int s = 64; s >= 1; s >>= 1) {
        if (j < s) { if (smin[j + s] < smin[j]) smin[j] = smin[j + s]; }
        __syncthreads();
    }
    unsigned minIdx = (unsigned)(smin[0] & 0xFFFFFFFFu);
    float wmin = wts[((size_t)b * NSQ + minIdx) * FF + f];

    // fused P-sum: counts channel
    {
        const float* src = part + (((size_t)b * CH + FF) * PP) * TT + j;
        float v = 0.f;
        for (int p = 0; p < PP; ++p) v += src[(size_t)p * TT];
        buf[0][j] = v;
    }
    __syncthreads();
    int cur = 0;
    for (int off = 1; off < TT; off <<= 1) {
        float v = buf[cur][j];
        if (j >= off) v += buf[cur][j - off];
        buf[cur ^ 1][j] = v;
        cur ^= 1;
        __syncthreads();
    }
    scnt[j] = buf[cur][j];
    __syncthreads();

    // fused P-sum: this block's feature channel
    {
        const float* src = part + (((size_t)b * CH + f) * PP) * TT + j;
        float v = 0.f;
        for (int p = 0; p < PP; ++p) v += src[(size_t)p * TT];
        buf[0][j] = v;
    }
    __syncthreads();
    cur = 0;
    for (int off = 1; off < TT; off <<= 1) {
        float v = buf[cur][j];
        if (j >= off) v += buf[cur][j - off];
        buf[cur ^ 1][j] = v;
        cur ^= 1;
        __syncthreads();
    }
    float Cj   = buf[cur][j];
    float Cjm1 = (j > 0) ? buf[cur][j - 1] : 0.f;
    float scj   = scnt[j];
    float scjm1 = (j > 0) ? scnt[j - 1] : 1.f;   // unused when j==0
    // reference quirk: counts==0 gathers cumsum_w[0] == weight of min element
    float csj   = (scj   == 0.f) ? wmin : Cj;
    float csjm1 = (j == 0) ? 0.f : ((scjm1 == 0.f) ? wmin : Cjm1);
    out[((size_t)b * TT + j) * FF + f] = csj - csjm1;
}

extern "C" void kernel_launch(void* const* d_in, const int* in_sizes, int n_in,
                              void* d_out, int out_size, void* d_ws, size_t ws_size,
                              hipStream_t stream)
{
    const float* inp  = (const float*)d_in[0];
    const float* bins = (const float*)d_in[1];
    const float* wts  = (const float*)d_in[2];
    float* out = (float*)d_out;

    char* w = (char*)d_ws;
    float* part    = (float*)w; w += (size_t)BB * CH * PP * TT * 4;  // 18.9 MB
    ull*   partMin = (ull*)w;

    histo_kernel<<<dim3(BB * PP), dim3(256), 0, stream>>>(
        inp, bins, wts, part, partMin);
    finalize_kernel<<<dim3(BB * FF), dim3(1024), 0, stream>>>(
        part, partMin, wts, out);
}